// Round 12
// baseline (419.181 us; speedup 1.0000x reference)
//
#include <hip/hip_runtime.h>
#include <math.h>

// ============ two-level counting sort (R8) + pre-scaled float4 gathers ============
// R11 = 418us. Top: k_gather_l2out 70.7us, VALUBusy 50% -- 8-lane slots replicate
// per-edge work (sorted[k] load, dv[row] gather, norm mul) x8. R12: (1) k_scale
// pre-folds dv[row]*w into the entry (one 6us pass, saves a random gather + mul in
// BOTH layers); (2) gathers remapped to 16 slots x 4 lanes x float4 (halves
// redundant VALU again, nit ~2). Sort build + xw1 unchanged (proven).
#define BS   128          // nodes per bucket
#define BSL  7
#define NBLK 1024         // edge-chunk blocks for count/scatter

typedef unsigned int uint;

// ---- pass 1: per-block histogram of bucket ids ----
__global__ __launch_bounds__(256) void k_bcount(const int* __restrict__ col,
                                                uint* __restrict__ cnt,
                                                int E, int NB, int chunk) {
    __shared__ uint bins[1024];
    for (int i = threadIdx.x; i < NB; i += 256) bins[i] = 0u;
    __syncthreads();
    int e0 = blockIdx.x * chunk, e1 = min(E, e0 + chunk);
    for (int e = e0 + threadIdx.x * 4; e < e1; e += 1024) {
        int4 c4;
        if (e + 3 < e1) c4 = *(const int4*)(col + e);
        else {
            c4.x = col[e];
            c4.y = (e + 1 < e1) ? col[e + 1] : -1;
            c4.z = (e + 2 < e1) ? col[e + 2] : -1;
            c4.w = (e + 3 < e1) ? col[e + 3] : -1;
        }
        if (c4.x >= 0) atomicAdd(&bins[c4.x >> BSL], 1u);
        if (c4.y >= 0) atomicAdd(&bins[c4.y >> BSL], 1u);
        if (c4.z >= 0) atomicAdd(&bins[c4.z >> BSL], 1u);
        if (c4.w >= 0) atomicAdd(&bins[c4.w >> BSL], 1u);
    }
    __syncthreads();
    for (int i = threadIdx.x; i < NB; i += 256)
        cnt[(size_t)i * NBLK + blockIdx.x] = bins[i];
}

// ---- pass 2: per bucket, exclusive scan over its NBLK block-counts + total ----
__global__ __launch_bounds__(256) void k_bprefix(uint* __restrict__ cnt,
                                                 uint* __restrict__ tot) {
    __shared__ uint s[256];
    uint* q = cnt + (size_t)blockIdx.x * NBLK;
    int t = threadIdx.x;
    uint v0 = q[t * 4], v1 = q[t * 4 + 1], v2 = q[t * 4 + 2], v3 = q[t * 4 + 3];
    uint s4 = v0 + v1 + v2 + v3;
    s[t] = s4;
    __syncthreads();
    for (int off = 1; off < 256; off <<= 1) {
        uint x = (t >= off) ? s[t - off] : 0u;
        __syncthreads();
        s[t] += x;
        __syncthreads();
    }
    uint excl = s[t] - s4;
    q[t * 4] = excl; q[t * 4 + 1] = excl + v0;
    q[t * 4 + 2] = excl + v0 + v1; q[t * 4 + 3] = excl + v0 + v1 + v2;
    if (t == 255) tot[blockIdx.x] = s[255];
}

// ---- pass 3: exclusive scan of bucket totals -> bbase[0..NB], bbase[NB]=E ----
__global__ __launch_bounds__(256) void k_scanT(const uint* __restrict__ tot,
                                               uint* __restrict__ bbase, int NB) {
    __shared__ uint s[256];
    __shared__ uint carry;
    int t = threadIdx.x;
    if (t == 0) carry = 0;
    __syncthreads();
    for (int base = 0; base < NB; base += 256) {
        int i = base + t;
        uint v = (i < NB) ? tot[i] : 0u;
        s[t] = v;
        __syncthreads();
        for (int off = 1; off < 256; off <<= 1) {
            uint x = (t >= off) ? s[t - off] : 0u;
            __syncthreads();
            s[t] += x;
            __syncthreads();
        }
        uint c = carry;
        if (i < NB) bbase[i] = c + s[t] - v;
        __syncthreads();
        if (t == 255) carry = c + s[255];
        __syncthreads();
    }
    if (t == 0) bbase[NB] = carry;
}

// ---- pass 4: scatter edges to bucket order; entry=(row<<7|col_local, w) ----
__global__ __launch_bounds__(256) void k_bscatter(const int* __restrict__ row,
        const int* __restrict__ col, const float* __restrict__ w,
        const uint* __restrict__ cnt, const uint* __restrict__ bbase,
        int2* __restrict__ bsorted, int E, int NB, int chunk) {
    __shared__ uint cur[1024];
    for (int i = threadIdx.x; i < NB; i += 256)
        cur[i] = bbase[i] + cnt[(size_t)i * NBLK + blockIdx.x];
    __syncthreads();
    int e0 = blockIdx.x * chunk, e1 = min(E, e0 + chunk);
    for (int e = e0 + threadIdx.x * 4; e < e1; e += 1024) {
        int4 c4, r4;
        float4 w4;
        if (e + 3 < e1) {
            c4 = *(const int4*)(col + e);
            r4 = *(const int4*)(row + e);
            w4 = *(const float4*)(w + e);
        } else {
            c4.x = col[e]; r4.x = row[e]; w4.x = w[e];
            c4.y = (e + 1 < e1) ? col[e + 1] : -1; r4.y = (e + 1 < e1) ? row[e + 1] : 0;
            w4.y = (e + 1 < e1) ? w[e + 1] : 0.f;
            c4.z = (e + 2 < e1) ? col[e + 2] : -1; r4.z = (e + 2 < e1) ? row[e + 2] : 0;
            w4.z = (e + 2 < e1) ? w[e + 2] : 0.f;
            c4.w = -1; r4.w = 0; w4.w = 0.f;
        }
        int cc[4] = {c4.x, c4.y, c4.z, c4.w};
        int rr[4] = {r4.x, r4.y, r4.z, r4.w};
        float ww[4] = {w4.x, w4.y, w4.z, w4.w};
#pragma unroll
        for (int k = 0; k < 4; k++) {
            if (cc[k] >= 0) {
                uint slot = atomicAdd(&cur[cc[k] >> BSL], 1u);
                bsorted[slot] = make_int2((rr[k] << BSL) | (cc[k] & (BS - 1)),
                                          __float_as_int(ww[k]));
            }
        }
    }
}

// ---- pass 5: fine sort within bucket; fuses dv + per-node CSR offsets ----
__global__ __launch_bounds__(256) void k_fsort(const int2* __restrict__ bsorted,
        const uint* __restrict__ bbase, int2* __restrict__ fsorted,
        uint* __restrict__ nodeoff, float* __restrict__ dv, int N) {
    __shared__ uint hist[BS];
    __shared__ float wa[BS];
    __shared__ uint cur[BS];
    int b = blockIdx.x, t = threadIdx.x;
    if (t < BS) { hist[t] = 0u; wa[t] = 0.f; }
    __syncthreads();
    uint s0 = bbase[b], s1 = bbase[b + 1];
    for (uint k = s0 + t; k < s1; k += 256) {
        int2 v = bsorted[k];
        int lo = v.x & (BS - 1);
        atomicAdd(&hist[lo], 1u);
        atomicAdd(&wa[lo], __int_as_float(v.y));
    }
    __syncthreads();
    uint vv = (t < BS) ? hist[t] : 0u;          // Hillis-Steele over 128
    for (int off = 1; off < BS; off <<= 1) {
        uint x = (t < BS && t >= off) ? hist[t - off] : 0u;
        __syncthreads();
        if (t < BS) hist[t] += x;
        __syncthreads();
    }
    if (t < BS) {
        uint base = s0 + (hist[t] - vv);        // exclusive prefix
        cur[t] = base;
        nodeoff[(b << BSL) + t] = base;
        int n = (b << BSL) + t;
        if (n < N) dv[n] = rsqrtf(1.f + wa[t]); // self-loop weight 1
    }
    __syncthreads();
    for (uint k = s0 + t; k < s1; k += 256) {
        int2 v = bsorted[k];
        int lo = v.x & (BS - 1);
        uint slot = atomicAdd(&cur[lo], 1u);
        fsorted[slot] = make_int2(((uint)v.x) >> BSL, v.y);   // plain row
    }
}

// ---- pre-scale: entry.w <- dv[row] * w (saves a random dv gather in BOTH layers) ----
__global__ __launch_bounds__(256) void k_scale(int2* __restrict__ fsorted,
                                               const float* __restrict__ dv, int E) {
    for (int i = blockIdx.x * 256 + threadIdx.x; i < E; i += gridDim.x * 256) {
        int2 v = fsorted[i];
        fsorted[i].y = __float_as_int(dv[v.x] * __int_as_float(v.y));
    }
}

// ---------------- x @ W1: coalesced quad-lane-per-row (proven R11) ----------------
#define WST 28
__global__ __launch_bounds__(256) void k_xw1(const float* __restrict__ x,
                                             const float* __restrict__ W1,
                                             float* __restrict__ h, int N) {
    __shared__ float wsh[256 * WST];
    int t = threadIdx.x;
    for (int i = t; i < 4096; i += 256)
        wsh[(i >> 4) * WST + (i & 15)] = W1[i];
    __syncthreads();

    int lane = t & 63, wv = t >> 6;
    int q = lane & 3;
    int r = blockIdx.x * 64 + wv * 16 + (lane >> 2);
    float acc[16];
#pragma unroll
    for (int j = 0; j < 16; j++) acc[j] = 0.f;

    if (r < N) {
        const float4* xr = (const float4*)(x + (size_t)r * 256);
#pragma unroll 4
        for (int k4 = 0; k4 < 16; k4++) {
            float4 xv = xr[q + k4 * 4];
            int kbase = (q + 4 * k4) * 4;
#pragma unroll
            for (int kk = 0; kk < 4; kk++) {
                float xs = (&xv.x)[kk];
                const float* wr = &wsh[(kbase + kk) * WST];
#pragma unroll
                for (int jq = 0; jq < 4; jq++) {
                    float4 wv4 = *(const float4*)(wr + jq * 4);
                    acc[jq * 4 + 0] = fmaf(xs, wv4.x, acc[jq * 4 + 0]);
                    acc[jq * 4 + 1] = fmaf(xs, wv4.y, acc[jq * 4 + 1]);
                    acc[jq * 4 + 2] = fmaf(xs, wv4.z, acc[jq * 4 + 2]);
                    acc[jq * 4 + 3] = fmaf(xs, wv4.w, acc[jq * 4 + 3]);
                }
            }
        }
    }
#pragma unroll
    for (int j = 0; j < 16; j++) {      // reduce across quad (unconditional)
        acc[j] += __shfl_xor(acc[j], 1);
        acc[j] += __shfl_xor(acc[j], 2);
    }
    if (q == 0 && r < N) {
        float4* ho = (float4*)(h + (size_t)r * 16);
#pragma unroll
        for (int jq = 0; jq < 4; jq++)
            ho[jq] = make_float4(acc[jq * 4], acc[jq * 4 + 1],
                                 acc[jq * 4 + 2], acc[jq * 4 + 3]);
    }
}

// ---- layer1: wave per node; 16 slots x 4 lanes x float4; prefetch ----
__global__ __launch_bounds__(256) void k_gather_l1(const int2* __restrict__ sorted,
        const uint* __restrict__ no, const float* __restrict__ dv,
        const float* __restrict__ h, const float* __restrict__ b1,
        float* __restrict__ ho, int N) {
    int wave = threadIdx.x >> 6;
    int node = blockIdx.x * 4 + wave;
    if (node >= N) return;
    int lane = threadIdx.x & 63;
    int slot = lane >> 2, f4 = lane & 3;
    uint s0 = no[node], s1 = no[node + 1];
    float dvn = dv[node];
    float4 acc = make_float4(0.f, 0.f, 0.f, 0.f);
    uint k = s0 + slot;
    int2 pr = (k < s1) ? sorted[k] : make_int2(0, 0);   // w=0 for dummy
    int nit = (int)((s1 - s0 + 15) >> 4);
    for (int it = 0; it < nit; ++it) {
        uint kn = k + 16;
        int2 prn = (kn < s1) ? sorted[kn] : make_int2(0, 0);
        float nr = __int_as_float(pr.y) * dvn;          // pre-scaled dv[row]*w
        float4 hv = *(const float4*)(h + (size_t)pr.x * 16 + f4 * 4);
        acc.x = fmaf(nr, hv.x, acc.x);
        acc.y = fmaf(nr, hv.y, acc.y);
        acc.z = fmaf(nr, hv.z, acc.z);
        acc.w = fmaf(nr, hv.w, acc.w);
        pr = prn; k = kn;
    }
#pragma unroll
    for (int off = 4; off < 64; off <<= 1) {
        acc.x += __shfl_xor(acc.x, off);
        acc.y += __shfl_xor(acc.y, off);
        acc.z += __shfl_xor(acc.z, off);
        acc.w += __shfl_xor(acc.w, off);
    }
    float4 hs = *(const float4*)(h + (size_t)node * 16 + f4 * 4);
    float4 bb = *(const float4*)(b1 + f4 * 4);
    float s2 = dvn * dvn;
    acc.x = fmaxf(fmaf(s2, hs.x, acc.x) + bb.x, 0.f);
    acc.y = fmaxf(fmaf(s2, hs.y, acc.y) + bb.y, 0.f);
    acc.z = fmaxf(fmaf(s2, hs.z, acc.z) + bb.z, 0.f);
    acc.w = fmaxf(fmaf(s2, hs.w, acc.w) + bb.w, 0.f);
    if (slot == 0) *(float4*)(ho + (size_t)node * 16 + f4 * 4) = acc;
}

// ---- layer2: same gather + fused @W2 + b2 + log_softmax ----
__global__ __launch_bounds__(256) void k_gather_l2out(const int2* __restrict__ sorted,
        const uint* __restrict__ no, const float* __restrict__ dv,
        const float* __restrict__ h, const float* __restrict__ W2,
        const float* __restrict__ b2, float* __restrict__ out, int N) {
    int wave = threadIdx.x >> 6;
    int node = blockIdx.x * 4 + wave;
    if (node >= N) return;
    int lane = threadIdx.x & 63;
    int slot = lane >> 2, f4 = lane & 3;
    uint s0 = no[node], s1 = no[node + 1];
    float dvn = dv[node];
    float4 acc = make_float4(0.f, 0.f, 0.f, 0.f);
    uint k = s0 + slot;
    int2 pr = (k < s1) ? sorted[k] : make_int2(0, 0);
    int nit = (int)((s1 - s0 + 15) >> 4);
    for (int it = 0; it < nit; ++it) {
        uint kn = k + 16;
        int2 prn = (kn < s1) ? sorted[kn] : make_int2(0, 0);
        float nr = __int_as_float(pr.y) * dvn;
        float4 hv = *(const float4*)(h + (size_t)pr.x * 16 + f4 * 4);
        acc.x = fmaf(nr, hv.x, acc.x);
        acc.y = fmaf(nr, hv.y, acc.y);
        acc.z = fmaf(nr, hv.z, acc.z);
        acc.w = fmaf(nr, hv.w, acc.w);
        pr = prn; k = kn;
    }
#pragma unroll
    for (int off = 4; off < 64; off <<= 1) {
        acc.x += __shfl_xor(acc.x, off);
        acc.y += __shfl_xor(acc.y, off);
        acc.z += __shfl_xor(acc.z, off);
        acc.w += __shfl_xor(acc.w, off);
    }
    float4 hs = *(const float4*)(h + (size_t)node * 16 + f4 * 4);
    float s2 = dvn * dvn;
    acc.x = fmaf(s2, hs.x, acc.x);      // every lane now holds its f4 quarter
    acc.y = fmaf(s2, hs.y, acc.y);
    acc.z = fmaf(s2, hs.z, acc.z);
    acc.w = fmaf(s2, hs.w, acc.w);

    float aj[16];
#pragma unroll
    for (int q = 0; q < 4; q++) {       // lane q<4 holds features q*4..q*4+3
        aj[q * 4 + 0] = __shfl(acc.x, q);
        aj[q * 4 + 1] = __shfl(acc.y, q);
        aj[q * 4 + 2] = __shfl(acc.z, q);
        aj[q * 4 + 3] = __shfl(acc.w, q);
    }
    float logit = -INFINITY;
    if (lane < 40) {
        logit = b2[lane];
#pragma unroll
        for (int q = 0; q < 16; q++) logit += aj[q] * W2[q * 40 + lane];
    }
    float m = logit;
#pragma unroll
    for (int off = 32; off; off >>= 1) m = fmaxf(m, __shfl_xor(m, off));
    float ex = (lane < 40) ? expf(logit - m) : 0.f;
    float ssum = ex;
#pragma unroll
    for (int off = 32; off; off >>= 1) ssum += __shfl_xor(ssum, off);
    if (lane < 40) out[(size_t)node * 40 + lane] = logit - m - logf(ssum);
}

extern "C" void kernel_launch(void* const* d_in, const int* in_sizes, int n_in,
                              void* d_out, int out_size, void* d_ws, size_t ws_size,
                              hipStream_t stream) {
    const float* x  = (const float*)d_in[0];
    const int*   ei = (const int*)d_in[1];
    const float* ew = (const float*)d_in[2];
    const float* W1 = (const float*)d_in[3];
    const float* b1 = (const float*)d_in[4];
    const float* W2 = (const float*)d_in[5];
    const float* b2 = (const float*)d_in[6];
    float* out = (float*)d_out;

    int N = in_sizes[0] / 256;
    int E = in_sizes[2];
    const int* row = ei;
    const int* col = ei + E;

    int NB = (N + BS - 1) >> BSL;                 // 782 buckets
    int chunk = (((E + NBLK - 1) / NBLK) + 3) & ~3;

    // workspace (u32 units), peak ~55MB (R8 proven layout):
    //   fsorted 2E | bsorted 2E (dead after fsort -> reused for h, h1)
    //   | cnt NB*NBLK | tot NB | bbase NB+1 | nodeoff NB*BS+1 | dv N
    uint* ws32 = (uint*)d_ws;
    int2* fsorted = (int2*)ws32;
    int2* bsorted = (int2*)(ws32 + 2 * (size_t)E);
    uint* cnt     = ws32 + 4 * (size_t)E;
    uint* tot     = cnt + (size_t)NB * NBLK;
    uint* bbase   = tot + NB;
    uint* nodeoff = bbase + NB + 1;
    float* dv     = (float*)(nodeoff + (size_t)NB * BS + 1);
    float* h      = (float*)bsorted;              // reuse after k_fsort
    float* h1     = h + (size_t)N * 16;

    k_bcount  <<<NBLK, 256, 0, stream>>>(col, cnt, E, NB, chunk);
    k_bprefix <<<NB, 256, 0, stream>>>(cnt, tot);
    k_scanT   <<<1, 256, 0, stream>>>(tot, bbase, NB);
    k_bscatter<<<NBLK, 256, 0, stream>>>(row, col, ew, cnt, bbase, bsorted, E, NB, chunk);
    k_fsort   <<<NB, 256, 0, stream>>>(bsorted, bbase, fsorted, nodeoff, dv, N);
    k_scale   <<<2048, 256, 0, stream>>>(fsorted, dv, E);
    k_xw1     <<<(N + 63) / 64, 256, 0, stream>>>(x, W1, h, N);
    k_gather_l1   <<<(N + 3) / 4, 256, 0, stream>>>(fsorted, nodeoff, dv, h, b1, h1, N);
    k_gather_l2out<<<(N + 3) / 4, 256, 0, stream>>>(fsorted, nodeoff, dv, h1, W2, b2, out, N);
}

// Round 13
// 413.106 us; speedup vs baseline: 1.0147x; 1.0147x over previous
//
#include <hip/hip_runtime.h>
#include <hip/hip_fp16.h>
#include <math.h>

// ============ two-level counting sort (R8) + fp16-h float4 gathers ============
// R12 = 419us. Gathers' cost structure (R11 counters): FETCH 121MB each, ~96MB =
// random 64B h-row re-fetch (6.4MB fp32 h > 4MB per-XCD L2 -> 60% miss to HBM).
// R13: h/h1 stored fp16 (3.2MB row arrays, 32B rows) -> payload halves AND h fits
// per-XCD L2 (misses become compulsory-only, ~200cyc L2 hits). Accum stays fp32.
// Sort build + gather structure + xw1 compute unchanged (proven).
#define BS   128          // nodes per bucket
#define BSL  7
#define NBLK 1024         // edge-chunk blocks for count/scatter

typedef unsigned int uint;

// ---- pass 1: per-block histogram of bucket ids ----
__global__ __launch_bounds__(256) void k_bcount(const int* __restrict__ col,
                                                uint* __restrict__ cnt,
                                                int E, int NB, int chunk) {
    __shared__ uint bins[1024];
    for (int i = threadIdx.x; i < NB; i += 256) bins[i] = 0u;
    __syncthreads();
    int e0 = blockIdx.x * chunk, e1 = min(E, e0 + chunk);
    for (int e = e0 + threadIdx.x * 4; e < e1; e += 1024) {
        int4 c4;
        if (e + 3 < e1) c4 = *(const int4*)(col + e);
        else {
            c4.x = col[e];
            c4.y = (e + 1 < e1) ? col[e + 1] : -1;
            c4.z = (e + 2 < e1) ? col[e + 2] : -1;
            c4.w = (e + 3 < e1) ? col[e + 3] : -1;
        }
        if (c4.x >= 0) atomicAdd(&bins[c4.x >> BSL], 1u);
        if (c4.y >= 0) atomicAdd(&bins[c4.y >> BSL], 1u);
        if (c4.z >= 0) atomicAdd(&bins[c4.z >> BSL], 1u);
        if (c4.w >= 0) atomicAdd(&bins[c4.w >> BSL], 1u);
    }
    __syncthreads();
    for (int i = threadIdx.x; i < NB; i += 256)
        cnt[(size_t)i * NBLK + blockIdx.x] = bins[i];
}

// ---- pass 2: per bucket, exclusive scan over its NBLK block-counts + total ----
__global__ __launch_bounds__(256) void k_bprefix(uint* __restrict__ cnt,
                                                 uint* __restrict__ tot) {
    __shared__ uint s[256];
    uint* q = cnt + (size_t)blockIdx.x * NBLK;
    int t = threadIdx.x;
    uint v0 = q[t * 4], v1 = q[t * 4 + 1], v2 = q[t * 4 + 2], v3 = q[t * 4 + 3];
    uint s4 = v0 + v1 + v2 + v3;
    s[t] = s4;
    __syncthreads();
    for (int off = 1; off < 256; off <<= 1) {
        uint x = (t >= off) ? s[t - off] : 0u;
        __syncthreads();
        s[t] += x;
        __syncthreads();
    }
    uint excl = s[t] - s4;
    q[t * 4] = excl; q[t * 4 + 1] = excl + v0;
    q[t * 4 + 2] = excl + v0 + v1; q[t * 4 + 3] = excl + v0 + v1 + v2;
    if (t == 255) tot[blockIdx.x] = s[255];
}

// ---- pass 3: exclusive scan of bucket totals -> bbase[0..NB], bbase[NB]=E ----
__global__ __launch_bounds__(256) void k_scanT(const uint* __restrict__ tot,
                                               uint* __restrict__ bbase, int NB) {
    __shared__ uint s[256];
    __shared__ uint carry;
    int t = threadIdx.x;
    if (t == 0) carry = 0;
    __syncthreads();
    for (int base = 0; base < NB; base += 256) {
        int i = base + t;
        uint v = (i < NB) ? tot[i] : 0u;
        s[t] = v;
        __syncthreads();
        for (int off = 1; off < 256; off <<= 1) {
            uint x = (t >= off) ? s[t - off] : 0u;
            __syncthreads();
            s[t] += x;
            __syncthreads();
        }
        uint c = carry;
        if (i < NB) bbase[i] = c + s[t] - v;
        __syncthreads();
        if (t == 255) carry = c + s[255];
        __syncthreads();
    }
    if (t == 0) bbase[NB] = carry;
}

// ---- pass 4: scatter edges to bucket order; entry=(row<<7|col_local, w) ----
__global__ __launch_bounds__(256) void k_bscatter(const int* __restrict__ row,
        const int* __restrict__ col, const float* __restrict__ w,
        const uint* __restrict__ cnt, const uint* __restrict__ bbase,
        int2* __restrict__ bsorted, int E, int NB, int chunk) {
    __shared__ uint cur[1024];
    for (int i = threadIdx.x; i < NB; i += 256)
        cur[i] = bbase[i] + cnt[(size_t)i * NBLK + blockIdx.x];
    __syncthreads();
    int e0 = blockIdx.x * chunk, e1 = min(E, e0 + chunk);
    for (int e = e0 + threadIdx.x * 4; e < e1; e += 1024) {
        int4 c4, r4;
        float4 w4;
        if (e + 3 < e1) {
            c4 = *(const int4*)(col + e);
            r4 = *(const int4*)(row + e);
            w4 = *(const float4*)(w + e);
        } else {
            c4.x = col[e]; r4.x = row[e]; w4.x = w[e];
            c4.y = (e + 1 < e1) ? col[e + 1] : -1; r4.y = (e + 1 < e1) ? row[e + 1] : 0;
            w4.y = (e + 1 < e1) ? w[e + 1] : 0.f;
            c4.z = (e + 2 < e1) ? col[e + 2] : -1; r4.z = (e + 2 < e1) ? row[e + 2] : 0;
            w4.z = (e + 2 < e1) ? w[e + 2] : 0.f;
            c4.w = -1; r4.w = 0; w4.w = 0.f;
        }
        int cc[4] = {c4.x, c4.y, c4.z, c4.w};
        int rr[4] = {r4.x, r4.y, r4.z, r4.w};
        float ww[4] = {w4.x, w4.y, w4.z, w4.w};
#pragma unroll
        for (int k = 0; k < 4; k++) {
            if (cc[k] >= 0) {
                uint slot = atomicAdd(&cur[cc[k] >> BSL], 1u);
                bsorted[slot] = make_int2((rr[k] << BSL) | (cc[k] & (BS - 1)),
                                          __float_as_int(ww[k]));
            }
        }
    }
}

// ---- pass 5: fine sort within bucket; fuses dv + per-node CSR offsets ----
__global__ __launch_bounds__(256) void k_fsort(const int2* __restrict__ bsorted,
        const uint* __restrict__ bbase, int2* __restrict__ fsorted,
        uint* __restrict__ nodeoff, float* __restrict__ dv, int N) {
    __shared__ uint hist[BS];
    __shared__ float wa[BS];
    __shared__ uint cur[BS];
    int b = blockIdx.x, t = threadIdx.x;
    if (t < BS) { hist[t] = 0u; wa[t] = 0.f; }
    __syncthreads();
    uint s0 = bbase[b], s1 = bbase[b + 1];
    for (uint k = s0 + t; k < s1; k += 256) {
        int2 v = bsorted[k];
        int lo = v.x & (BS - 1);
        atomicAdd(&hist[lo], 1u);
        atomicAdd(&wa[lo], __int_as_float(v.y));
    }
    __syncthreads();
    uint vv = (t < BS) ? hist[t] : 0u;          // Hillis-Steele over 128
    for (int off = 1; off < BS; off <<= 1) {
        uint x = (t < BS && t >= off) ? hist[t - off] : 0u;
        __syncthreads();
        if (t < BS) hist[t] += x;
        __syncthreads();
    }
    if (t < BS) {
        uint base = s0 + (hist[t] - vv);        // exclusive prefix
        cur[t] = base;
        nodeoff[(b << BSL) + t] = base;
        int n = (b << BSL) + t;
        if (n < N) dv[n] = rsqrtf(1.f + wa[t]); // self-loop weight 1
    }
    __syncthreads();
    for (uint k = s0 + t; k < s1; k += 256) {
        int2 v = bsorted[k];
        int lo = v.x & (BS - 1);
        uint slot = atomicAdd(&cur[lo], 1u);
        fsorted[slot] = make_int2(((uint)v.x) >> BSL, v.y);   // plain row
    }
}

// ---- pre-scale: entry.w <- dv[row] * w (saves a random dv gather in BOTH layers) ----
__global__ __launch_bounds__(256) void k_scale(int2* __restrict__ fsorted,
                                               const float* __restrict__ dv, int E) {
    for (int i = blockIdx.x * 256 + threadIdx.x; i < E; i += gridDim.x * 256) {
        int2 v = fsorted[i];
        fsorted[i].y = __float_as_int(dv[v.x] * __int_as_float(v.y));
    }
}

// ---------------- x @ W1: coalesced quad-lane-per-row, fp16 output ----------------
#define WST 28
__global__ __launch_bounds__(256) void k_xw1(const float* __restrict__ x,
                                             const float* __restrict__ W1,
                                             __half* __restrict__ h, int N) {
    __shared__ float wsh[256 * WST];
    int t = threadIdx.x;
    for (int i = t; i < 4096; i += 256)
        wsh[(i >> 4) * WST + (i & 15)] = W1[i];
    __syncthreads();

    int lane = t & 63, wv = t >> 6;
    int q = lane & 3;
    int r = blockIdx.x * 64 + wv * 16 + (lane >> 2);
    float acc[16];
#pragma unroll
    for (int j = 0; j < 16; j++) acc[j] = 0.f;

    if (r < N) {
        const float4* xr = (const float4*)(x + (size_t)r * 256);
#pragma unroll 4
        for (int k4 = 0; k4 < 16; k4++) {
            float4 xv = xr[q + k4 * 4];
            int kbase = (q + 4 * k4) * 4;
#pragma unroll
            for (int kk = 0; kk < 4; kk++) {
                float xs = (&xv.x)[kk];
                const float* wr = &wsh[(kbase + kk) * WST];
#pragma unroll
                for (int jq = 0; jq < 4; jq++) {
                    float4 wv4 = *(const float4*)(wr + jq * 4);
                    acc[jq * 4 + 0] = fmaf(xs, wv4.x, acc[jq * 4 + 0]);
                    acc[jq * 4 + 1] = fmaf(xs, wv4.y, acc[jq * 4 + 1]);
                    acc[jq * 4 + 2] = fmaf(xs, wv4.z, acc[jq * 4 + 2]);
                    acc[jq * 4 + 3] = fmaf(xs, wv4.w, acc[jq * 4 + 3]);
                }
            }
        }
    }
#pragma unroll
    for (int j = 0; j < 16; j++) {      // reduce across quad (unconditional)
        acc[j] += __shfl_xor(acc[j], 1);
        acc[j] += __shfl_xor(acc[j], 2);
    }
    if (q == 0 && r < N) {
        __half2 hp[8];
#pragma unroll
        for (int jq = 0; jq < 8; jq++)
            hp[jq] = __floats2half2_rn(acc[jq * 2], acc[jq * 2 + 1]);
        uint4* ho = (uint4*)(h + (size_t)r * 16);     // 32B row, 16B-aligned
        ho[0] = *(uint4*)&hp[0];
        ho[1] = *(uint4*)&hp[4];
    }
}

// ---- layer1: wave per node; 16 slots x 4 lanes x 4 fp16 feats; prefetch ----
__global__ __launch_bounds__(256) void k_gather_l1(const int2* __restrict__ sorted,
        const uint* __restrict__ no, const float* __restrict__ dv,
        const __half* __restrict__ h, const float* __restrict__ b1,
        __half* __restrict__ ho, int N) {
    int wave = threadIdx.x >> 6;
    int node = blockIdx.x * 4 + wave;
    if (node >= N) return;
    int lane = threadIdx.x & 63;
    int slot = lane >> 2, f4 = lane & 3;
    uint s0 = no[node], s1 = no[node + 1];
    float dvn = dv[node];
    float4 acc = make_float4(0.f, 0.f, 0.f, 0.f);
    uint k = s0 + slot;
    int2 pr = (k < s1) ? sorted[k] : make_int2(0, 0);   // w=0 for dummy
    int nit = (int)((s1 - s0 + 15) >> 4);
    for (int it = 0; it < nit; ++it) {
        uint kn = k + 16;
        int2 prn = (kn < s1) ? sorted[kn] : make_int2(0, 0);
        float nr = __int_as_float(pr.y) * dvn;          // pre-scaled dv[row]*w
        uint2 hv = *(const uint2*)(h + (size_t)pr.x * 16 + f4 * 4);
        float2 fa = __half22float2(*(__half2*)&hv.x);
        float2 fb = __half22float2(*(__half2*)&hv.y);
        acc.x = fmaf(nr, fa.x, acc.x);
        acc.y = fmaf(nr, fa.y, acc.y);
        acc.z = fmaf(nr, fb.x, acc.z);
        acc.w = fmaf(nr, fb.y, acc.w);
        pr = prn; k = kn;
    }
#pragma unroll
    for (int off = 4; off < 64; off <<= 1) {
        acc.x += __shfl_xor(acc.x, off);
        acc.y += __shfl_xor(acc.y, off);
        acc.z += __shfl_xor(acc.z, off);
        acc.w += __shfl_xor(acc.w, off);
    }
    uint2 hsv = *(const uint2*)(h + (size_t)node * 16 + f4 * 4);
    float2 ha = __half22float2(*(__half2*)&hsv.x);
    float2 hb = __half22float2(*(__half2*)&hsv.y);
    float4 bb = *(const float4*)(b1 + f4 * 4);
    float s2 = dvn * dvn;
    acc.x = fmaxf(fmaf(s2, ha.x, acc.x) + bb.x, 0.f);
    acc.y = fmaxf(fmaf(s2, ha.y, acc.y) + bb.y, 0.f);
    acc.z = fmaxf(fmaf(s2, hb.x, acc.z) + bb.z, 0.f);
    acc.w = fmaxf(fmaf(s2, hb.y, acc.w) + bb.w, 0.f);
    if (slot == 0) {
        __half2 o0 = __floats2half2_rn(acc.x, acc.y);
        __half2 o1 = __floats2half2_rn(acc.z, acc.w);
        uint2 st;
        st.x = *(uint*)&o0; st.y = *(uint*)&o1;
        *(uint2*)(ho + (size_t)node * 16 + f4 * 4) = st;
    }
}

// ---- layer2: same gather + fused @W2 + b2 + log_softmax ----
__global__ __launch_bounds__(256) void k_gather_l2out(const int2* __restrict__ sorted,
        const uint* __restrict__ no, const float* __restrict__ dv,
        const __half* __restrict__ h, const float* __restrict__ W2,
        const float* __restrict__ b2, float* __restrict__ out, int N) {
    int wave = threadIdx.x >> 6;
    int node = blockIdx.x * 4 + wave;
    if (node >= N) return;
    int lane = threadIdx.x & 63;
    int slot = lane >> 2, f4 = lane & 3;
    uint s0 = no[node], s1 = no[node + 1];
    float dvn = dv[node];
    float4 acc = make_float4(0.f, 0.f, 0.f, 0.f);
    uint k = s0 + slot;
    int2 pr = (k < s1) ? sorted[k] : make_int2(0, 0);
    int nit = (int)((s1 - s0 + 15) >> 4);
    for (int it = 0; it < nit; ++it) {
        uint kn = k + 16;
        int2 prn = (kn < s1) ? sorted[kn] : make_int2(0, 0);
        float nr = __int_as_float(pr.y) * dvn;
        uint2 hv = *(const uint2*)(h + (size_t)pr.x * 16 + f4 * 4);
        float2 fa = __half22float2(*(__half2*)&hv.x);
        float2 fb = __half22float2(*(__half2*)&hv.y);
        acc.x = fmaf(nr, fa.x, acc.x);
        acc.y = fmaf(nr, fa.y, acc.y);
        acc.z = fmaf(nr, fb.x, acc.z);
        acc.w = fmaf(nr, fb.y, acc.w);
        pr = prn; k = kn;
    }
#pragma unroll
    for (int off = 4; off < 64; off <<= 1) {
        acc.x += __shfl_xor(acc.x, off);
        acc.y += __shfl_xor(acc.y, off);
        acc.z += __shfl_xor(acc.z, off);
        acc.w += __shfl_xor(acc.w, off);
    }
    uint2 hsv = *(const uint2*)(h + (size_t)node * 16 + f4 * 4);
    float2 ha = __half22float2(*(__half2*)&hsv.x);
    float2 hb = __half22float2(*(__half2*)&hsv.y);
    float s2 = dvn * dvn;
    acc.x = fmaf(s2, ha.x, acc.x);      // every lane holds its f4 quarter
    acc.y = fmaf(s2, ha.y, acc.y);
    acc.z = fmaf(s2, hb.x, acc.z);
    acc.w = fmaf(s2, hb.y, acc.w);

    float aj[16];
#pragma unroll
    for (int q = 0; q < 4; q++) {       // lane q<4 holds features q*4..q*4+3
        aj[q * 4 + 0] = __shfl(acc.x, q);
        aj[q * 4 + 1] = __shfl(acc.y, q);
        aj[q * 4 + 2] = __shfl(acc.z, q);
        aj[q * 4 + 3] = __shfl(acc.w, q);
    }
    float logit = -INFINITY;
    if (lane < 40) {
        logit = b2[lane];
#pragma unroll
        for (int q = 0; q < 16; q++) logit += aj[q] * W2[q * 40 + lane];
    }
    float m = logit;
#pragma unroll
    for (int off = 32; off; off >>= 1) m = fmaxf(m, __shfl_xor(m, off));
    float ex = (lane < 40) ? expf(logit - m) : 0.f;
    float ssum = ex;
#pragma unroll
    for (int off = 32; off; off >>= 1) ssum += __shfl_xor(ssum, off);
    if (lane < 40) out[(size_t)node * 40 + lane] = logit - m - logf(ssum);
}

extern "C" void kernel_launch(void* const* d_in, const int* in_sizes, int n_in,
                              void* d_out, int out_size, void* d_ws, size_t ws_size,
                              hipStream_t stream) {
    const float* x  = (const float*)d_in[0];
    const int*   ei = (const int*)d_in[1];
    const float* ew = (const float*)d_in[2];
    const float* W1 = (const float*)d_in[3];
    const float* b1 = (const float*)d_in[4];
    const float* W2 = (const float*)d_in[5];
    const float* b2 = (const float*)d_in[6];
    float* out = (float*)d_out;

    int N = in_sizes[0] / 256;
    int E = in_sizes[2];
    const int* row = ei;
    const int* col = ei + E;

    int NB = (N + BS - 1) >> BSL;                 // 782 buckets
    int chunk = (((E + NBLK - 1) / NBLK) + 3) & ~3;

    // workspace (u32 units), peak ~55MB (R8 proven layout):
    //   fsorted 2E | bsorted 2E (dead after fsort -> reused for fp16 h, h1)
    //   | cnt NB*NBLK | tot NB | bbase NB+1 | nodeoff NB*BS+1 | dv N
    uint* ws32 = (uint*)d_ws;
    int2* fsorted = (int2*)ws32;
    int2* bsorted = (int2*)(ws32 + 2 * (size_t)E);
    uint* cnt     = ws32 + 4 * (size_t)E;
    uint* tot     = cnt + (size_t)NB * NBLK;
    uint* bbase   = tot + NB;
    uint* nodeoff = bbase + NB + 1;
    float* dv     = (float*)(nodeoff + (size_t)NB * BS + 1);
    __half* h     = (__half*)bsorted;             // reuse after k_fsort (3.2MB)
    __half* h1    = h + (size_t)N * 16;           // 3.2MB

    k_bcount  <<<NBLK, 256, 0, stream>>>(col, cnt, E, NB, chunk);
    k_bprefix <<<NB, 256, 0, stream>>>(cnt, tot);
    k_scanT   <<<1, 256, 0, stream>>>(tot, bbase, NB);
    k_bscatter<<<NBLK, 256, 0, stream>>>(row, col, ew, cnt, bbase, bsorted, E, NB, chunk);
    k_fsort   <<<NB, 256, 0, stream>>>(bsorted, bbase, fsorted, nodeoff, dv, N);
    k_scale   <<<2048, 256, 0, stream>>>(fsorted, dv, E);
    k_xw1     <<<(N + 63) / 64, 256, 0, stream>>>(x, W1, h, N);
    k_gather_l1   <<<(N + 3) / 4, 256, 0, stream>>>(fsorted, nodeoff, dv, h, b1, h1, N);
    k_gather_l2out<<<(N + 3) / 4, 256, 0, stream>>>(fsorted, nodeoff, dv, h1, W2, b2, out, N);
}